// Round 2
// baseline (594.497 us; speedup 1.0000x reference)
//
#include <hip/hip_runtime.h>
#include <hip/hip_bf16.h>
#include <math.h>

#define NN 1536
#define TT 10
#define DD 64
#define NHEAD 4
#define HDIM 16
#define PP 1178880   // NN*(NN-1)/2
#define JSPLIT 4
#define JCHUNK (NN / JSPLIT)

// ws layout (float offsets)
#define WS_NODE0 0
#define WS_G1    98304
#define WS_G2    196608
#define WS_PART  294912              // 4*1536*64 = 393216 floats (overlaps GI/GJT, used before them)
#define WS_GI    294912              // 1536*128
#define WS_GJT   491520              // 128*1536
#define WS_W2T   688128              // 128*64
#define WS_TXYT  696320              // 20*1536

static __device__ __forceinline__ float dot64(const float* __restrict__ a,
                                              const float* __restrict__ b) {
    float s = 0.f;
#pragma unroll
    for (int c = 0; c < 64; c += 4) {
        float4 av = *reinterpret_cast<const float4*>(a + c);
        float4 bv = *reinterpret_cast<const float4*>(b + c);
        s = fmaf(av.x, bv.x, s);
        s = fmaf(av.y, bv.y, s);
        s = fmaf(av.z, bv.z, s);
        s = fmaf(av.w, bv.w, s);
    }
    return s;
}

// ---------------- Transformer encoder layer, one block per node ----------------
__global__ __launch_bounds__(64) void k_transformer(
    const float* __restrict__ traj,
    const float* __restrict__ wqkv, const float* __restrict__ bqkv,
    const float* __restrict__ wo,   const float* __restrict__ bo,
    const float* __restrict__ g1,   const float* __restrict__ b1,
    const float* __restrict__ fw1,  const float* __restrict__ fb1,
    const float* __restrict__ fw2,  const float* __restrict__ fb2,
    const float* __restrict__ g2,   const float* __restrict__ b2,
    float* __restrict__ node_out)
{
    __shared__ __align__(16) float xs[TT][DD];
    __shared__ __align__(16) float qkvs[TT][3 * DD];
    __shared__ __align__(16) float cs[TT][DD];
    __shared__ __align__(16) float ys[TT][DD];
    __shared__ float mv[TT][2];

    const int n = blockIdx.x, tid = threadIdx.x;
    const float* xg = traj + (size_t)n * TT * DD;

    for (int idx = tid; idx < TT * DD; idx += 64)
        xs[idx / DD][idx % DD] = xg[idx];
    __syncthreads();

    for (int idx = tid; idx < TT * 3 * DD; idx += 64) {
        int t = idx / (3 * DD), o = idx % (3 * DD);
        qkvs[t][o] = bqkv[o] + dot64(&xs[t][0], wqkv + o * DD);
    }
    __syncthreads();

    if (tid < NHEAD * TT) {
        int h = tid / TT, t = tid % TT;
        float sc[TT];
        float mx = -1e30f;
#pragma unroll
        for (int s = 0; s < TT; ++s) {
            float a = 0.f;
#pragma unroll
            for (int d = 0; d < HDIM; ++d)
                a = fmaf(qkvs[t][h * HDIM + d], qkvs[s][DD + h * HDIM + d], a);
            a *= 0.25f;
            sc[s] = a;
            mx = fmaxf(mx, a);
        }
        float den = 0.f;
#pragma unroll
        for (int s = 0; s < TT; ++s) { sc[s] = expf(sc[s] - mx); den += sc[s]; }
        float inv = 1.f / den;
#pragma unroll
        for (int d = 0; d < HDIM; ++d) {
            float a = 0.f;
#pragma unroll
            for (int s = 0; s < TT; ++s)
                a = fmaf(sc[s], qkvs[s][2 * DD + h * HDIM + d], a);
            cs[t][h * HDIM + d] = a * inv;
        }
    }
    __syncthreads();

    for (int idx = tid; idx < TT * DD; idx += 64) {
        int t = idx / DD, o = idx % DD;
        ys[t][o] = xs[t][o] + bo[o] + dot64(&cs[t][0], wo + o * DD);
    }
    __syncthreads();

    if (tid < TT) {
        float m = 0.f;
        for (int c = 0; c < DD; ++c) m += ys[tid][c];
        m *= (1.f / DD);
        float v = 0.f;
        for (int c = 0; c < DD; ++c) { float d = ys[tid][c] - m; v = fmaf(d, d, v); }
        v *= (1.f / DD);
        mv[tid][0] = m;
        mv[tid][1] = rsqrtf(v + 1e-5f);
    }
    __syncthreads();
    for (int idx = tid; idx < TT * DD; idx += 64) {
        int t = idx / DD, o = idx % DD;
        xs[t][o] = (ys[t][o] - mv[t][0]) * mv[t][1] * g1[o] + b1[o];
    }
    __syncthreads();

    for (int idx = tid; idx < TT * DD; idx += 64) {
        int t = idx / DD, p = idx % DD;
        cs[t][p] = fmaxf(fb1[p] + dot64(&xs[t][0], fw1 + p * DD), 0.f);
    }
    __syncthreads();

    for (int idx = tid; idx < TT * DD; idx += 64) {
        int t = idx / DD, o = idx % DD;
        ys[t][o] = xs[t][o] + fb2[o] + dot64(&cs[t][0], fw2 + o * DD);
    }
    __syncthreads();

    if (tid < TT) {
        float m = 0.f;
        for (int c = 0; c < DD; ++c) m += ys[tid][c];
        m *= (1.f / DD);
        float v = 0.f;
        for (int c = 0; c < DD; ++c) { float d = ys[tid][c] - m; v = fmaf(d, d, v); }
        v *= (1.f / DD);
        mv[tid][0] = m;
        mv[tid][1] = rsqrtf(v + 1e-5f);
    }
    __syncthreads();

    if (tid < DD) {
        float acc = 0.f;
#pragma unroll
        for (int t = 0; t < TT; ++t)
            acc += (ys[t][tid] - mv[t][0]) * mv[t][1];
        node_out[n * DD + tid] = acc * g2[tid] * (1.f / TT) + b2[tid];
    }
}

// ---------------- GCN: partial A@X over j-chunk ----------------
// grid (NN/8, JSPLIT), 256 threads: 8 rows x 32 channel-pairs
__global__ __launch_bounds__(256) void k_gcn_part(
    const float* __restrict__ A, const float* __restrict__ X,
    float* __restrict__ part)
{
    const int tid = threadIdx.x;
    const int r = tid >> 5;
    const int cp = tid & 31;
    const int i = blockIdx.x * 8 + r;
    const int j0 = blockIdx.y * JCHUNK;

    const float* arow = A + (size_t)i * NN + j0;
    const float* xp = X + (size_t)j0 * 64 + 2 * cp;

    float a0 = 0.f, a1 = 0.f;
#pragma unroll 4
    for (int j = 0; j < JCHUNK; ++j) {
        float av = arow[j];
        float2 xv = *reinterpret_cast<const float2*>(xp + (size_t)j * 64);
        a0 = fmaf(av, xv.x, a0);
        a1 = fmaf(av, xv.y, a1);
    }
    float2* op = reinterpret_cast<float2*>(part + ((size_t)blockIdx.y * NN + i) * 64 + 2 * cp);
    *op = make_float2(a0, a1);
}

// ---------------- GCN: reduce partials, apply W^T + bias + relu ----------------
// grid NN/4, 256 threads: 4 rows x 64 outputs
__global__ __launch_bounds__(256) void k_gcn_red(
    const float* __restrict__ part, const float* __restrict__ W,
    const float* __restrict__ b, float* __restrict__ Y)
{
    __shared__ __align__(16) float yrow[4][68];
    const int o = threadIdx.x & 63, r = threadIdx.x >> 6;
    const int i = blockIdx.x * 4 + r;

    float s = 0.f;
#pragma unroll
    for (int jc = 0; jc < JSPLIT; ++jc)
        s += part[((size_t)jc * NN + i) * 64 + o];
    yrow[r][o] = s;
    __syncthreads();

    float z = b[o] + dot64(&yrow[r][0], W + o * 64);
    Y[(size_t)i * 64 + o] = fmaxf(z, 0.f);
}

// ---------------- prep A: gi table (row-major, per-i) ----------------
__global__ __launch_bounds__(128) void k_prep_a(
    const float* __restrict__ node, const float* __restrict__ e_w1,
    float* __restrict__ gi_t)
{
    __shared__ __align__(16) float ns[64];
    const int b = blockIdx.x;
    if (threadIdx.x < 64) ns[threadIdx.x] = node[b * 64 + threadIdx.x];
    __syncthreads();
    const int o = threadIdx.x;
    gi_t[(size_t)b * 128 + o] = dot64(ns, e_w1 + o * 138);
}

// ---------------- prep B: gjT (transposed), w2t, txyT ----------------
__global__ __launch_bounds__(256) void k_prep_b(
    const float* __restrict__ node, const float* __restrict__ e_w1,
    const float* __restrict__ e_w2, const float* __restrict__ traj,
    float* __restrict__ gjT, float* __restrict__ w2t, float* __restrict__ txyT)
{
    const int b = blockIdx.x;
    if (b < 128) {
        // one block per output o; threads sweep j -> coalesced writes
        const int o = b;
        const float* w = e_w1 + o * 138 + 64;
        for (int j = threadIdx.x; j < NN; j += 256)
            gjT[(size_t)o * NN + j] = dot64(node + (size_t)j * 64, w);
    } else if (b == 128) {
        for (int idx = threadIdx.x; idx < 128 * 64; idx += 256) {
            int o = idx >> 6, m = idx & 63;
            w2t[idx] = e_w2[m * 128 + o];
        }
    } else {
        const int tc = b - 129;       // 0..19
        const int t = tc >> 1, c = tc & 1;
        for (int j = threadIdx.x; j < NN; j += 256)
            txyT[(size_t)tc * NN + j] = traj[((size_t)j * TT + t) * DD + c];
    }
}

// ---------------- edge predictor: 2 threads per pair (m-split) ----------------
// grid (NN-1, 12), 256 threads: 128 pairs, mhalf = tid>>7
__global__ __launch_bounds__(256) void k_edge(
    const float* __restrict__ txyT,
    const float* __restrict__ gi_t, const float* __restrict__ gjT,
    const float* __restrict__ e_w1, const float* __restrict__ e_b1,
    const float* __restrict__ w2t,  const float* __restrict__ e_b2,
    const float* __restrict__ e_w3, const float* __restrict__ e_b3,
    float* __restrict__ out)
{
    __shared__ float hs[128][11];
    __shared__ float zs[128];

    const int i = blockIdx.x;
    const int jbase = i + 1 + blockIdx.y * 128;
    if (jbase >= NN) return;

    const int tid = threadIdx.x;
    const int pl = tid & 127;
    const int mh = __builtin_amdgcn_readfirstlane(tid >> 7);
    const int j = jbase + pl;
    const bool valid = (j < NN);
    const int jj = valid ? j : (NN - 1);
    const int p = i * (NN - 1) - (i * (i - 1)) / 2 + (j - i - 1);

    // phase 0: hist + dmin (one thread per pair)
    if (tid < 128) {
        float h[10];
        float dmin = 3.4e38f;
#pragma unroll
        for (int t = 0; t < 10; ++t) {
            float dx = txyT[(size_t)(2 * t) * NN + i] - txyT[(size_t)(2 * t) * NN + jj];
            float dy = txyT[(size_t)(2 * t + 1) * NN + i] - txyT[(size_t)(2 * t + 1) * NN + jj];
            float d = sqrtf(fmaf(dx, dx, dy * dy));
            dmin = fminf(dmin, d);
            h[t] = 1.f / (1.f + expf(50.f - 10.f * d));
            hs[pl][t] = h[t];
        }
        if (valid) {
            out[PP + (size_t)p] = dmin;
            float* hp = out + 2 * (size_t)PP + (size_t)p * 10;
#pragma unroll
            for (int t = 0; t < 10; ++t) hp[t] = h[t];
        }
    }
    __syncthreads();

    float hist[10];
#pragma unroll
    for (int t = 0; t < 10; ++t) hist[t] = hs[pl][t];

    float h2[32];
    const float* b2p = e_b2 + mh * 32;
#pragma unroll
    for (int m = 0; m < 32; ++m) h2[m] = b2p[m];

    const float* gi_row = gi_t + (size_t)i * 128;   // wave-uniform -> scalar path

#pragma unroll 4
    for (int o = 0; o < 128; ++o) {
        float a = e_b1[o] + gi_row[o] + gjT[(size_t)o * NN + jj];
        const float* wh = e_w1 + o * 138 + 128;     // uniform -> scalar
#pragma unroll
        for (int t = 0; t < 10; ++t) a = fmaf(hist[t], wh[t], a);
        a = fmaxf(a, 0.f);
        const float* w2 = w2t + o * 64 + mh * 32;   // uniform -> scalar
#pragma unroll
        for (int m = 0; m < 32; ++m) h2[m] = fmaf(a, w2[m], h2[m]);
    }

    const float* w3 = e_w3 + mh * 32;
    float z = 0.f;
#pragma unroll
    for (int m = 0; m < 32; ++m) z = fmaf(fmaxf(h2[m], 0.f), w3[m], z);

    if (mh) zs[pl] = z;
    __syncthreads();
    if (!mh && valid) {
        float zt = z + zs[pl] + e_b3[0];
        out[p] = 1.f / (1.f + expf(-zt));
    }
}

extern "C" void kernel_launch(void* const* d_in, const int* in_sizes, int n_in,
                              void* d_out, int out_size, void* d_ws, size_t ws_size,
                              hipStream_t stream) {
    const float* traj   = (const float*)d_in[0];
    const float* adj    = (const float*)d_in[1];
    const float* w_in   = (const float*)d_in[2];
    const float* b_in   = (const float*)d_in[3];
    const float* w_out  = (const float*)d_in[4];
    const float* b_out  = (const float*)d_in[5];
    const float* ln1g   = (const float*)d_in[6];
    const float* ln1b   = (const float*)d_in[7];
    const float* fw1    = (const float*)d_in[8];
    const float* fb1    = (const float*)d_in[9];
    const float* fw2    = (const float*)d_in[10];
    const float* fb2    = (const float*)d_in[11];
    const float* ln2g   = (const float*)d_in[12];
    const float* ln2b   = (const float*)d_in[13];
    const float* gcn_w  = (const float*)d_in[14];
    const float* gcn_b  = (const float*)d_in[15];
    const float* e_w1   = (const float*)d_in[16];
    const float* e_b1   = (const float*)d_in[17];
    const float* e_w2   = (const float*)d_in[18];
    const float* e_b2   = (const float*)d_in[19];
    const float* e_w3   = (const float*)d_in[20];
    const float* e_b3   = (const float*)d_in[21];

    float* ws    = (float*)d_ws;
    float* node0 = ws + WS_NODE0;
    float* g1b   = ws + WS_G1;
    float* g2b   = ws + WS_G2;
    float* partb = ws + WS_PART;
    float* gi    = ws + WS_GI;
    float* gjT   = ws + WS_GJT;
    float* w2t   = ws + WS_W2T;
    float* txyT  = ws + WS_TXYT;

    k_transformer<<<NN, 64, 0, stream>>>(traj, w_in, b_in, w_out, b_out,
                                         ln1g, ln1b, fw1, fb1, fw2, fb2,
                                         ln2g, ln2b, node0);

    dim3 pgrid(NN / 8, JSPLIT);
    k_gcn_part<<<pgrid, 256, 0, stream>>>(adj, node0, partb);
    k_gcn_red<<<NN / 4, 256, 0, stream>>>(partb, gcn_w, gcn_b, g1b);
    k_gcn_part<<<pgrid, 256, 0, stream>>>(adj, g1b, partb);
    k_gcn_red<<<NN / 4, 256, 0, stream>>>(partb, gcn_w + 4096, gcn_b + 64, g2b);
    k_gcn_part<<<pgrid, 256, 0, stream>>>(adj, g2b, partb);
    k_gcn_red<<<NN / 4, 256, 0, stream>>>(partb, gcn_w + 8192, gcn_b + 128, g1b);

    k_prep_a<<<NN, 128, 0, stream>>>(g1b, e_w1, gi);
    k_prep_b<<<149, 256, 0, stream>>>(g1b, e_w1, e_w2, traj, gjT, w2t, txyT);

    dim3 egrid(NN - 1, 12);
    k_edge<<<egrid, 256, 0, stream>>>(txyT, gi, gjT, e_w1, e_b1, w2t, e_b2,
                                      e_w3, e_b3, (float*)d_out);
}